// Round 1
// baseline (1965.384 us; speedup 1.0000x reference)
//
#include <hip/hip_runtime.h>

#define HH 64
#define T_ENC 20
#define T_DEC 30
#define EPW 8               // batch elements per wave
#define WAVES 4             // waves per block
#define EPB (EPW * WAVES)   // 32 elements per block

#if __has_builtin(__builtin_amdgcn_exp2f)
#define EXP2F(x) __builtin_amdgcn_exp2f(x)
#else
#define EXP2F(x) exp2f(x)
#endif
#if __has_builtin(__builtin_amdgcn_rcpf)
#define RCPF(x) __builtin_amdgcn_rcpf(x)
#else
#define RCPF(x) (1.0f / (x))
#endif

__device__ __forceinline__ float rdlane(float v, int l) {
  return __uint_as_float(__builtin_amdgcn_readlane(__float_as_uint(v), l));
}

// sigmoid(x) = 1/(1+2^(-x*log2e));  v_exp_f32 + v_rcp_f32, ~1-2 ulp
__device__ __forceinline__ float fast_sigmoid(float x) {
  float e = EXP2F(-1.4426950408889634f * x);
  return RCPF(1.0f + e);
}
// tanh(x) = 1 - 2/(2^(2x*log2e)+1); handles +-inf overflow gracefully
__device__ __forceinline__ float fast_tanh(float x) {
  float e = EXP2F(2.8853900817779268f * x);
  return 1.0f - 2.0f * RCPF(e + 1.0f);
}

__global__ __launch_bounds__(256, 2)
void SinglePrediction_88493506167138_kernel(
    const float* __restrict__ x,         // [B][20][2]
    const float* __restrict__ W_ih_enc,  // [256][2]
    const float* __restrict__ W_hh_enc,  // [256][64]
    const float* __restrict__ b_ih_enc,  // [256]
    const float* __restrict__ b_hh_enc,  // [256]
    const float* __restrict__ W_ih_dec,  // [256][64]
    const float* __restrict__ W_hh_dec,  // [256][64]
    const float* __restrict__ b_ih_dec,  // [256]
    const float* __restrict__ b_hh_dec,  // [256]
    const float* __restrict__ W_emb,     // [2][64]
    const float* __restrict__ b_emb,     // [2]
    float* __restrict__ out)             // [B][30][2]
{
  // LDS: 65536 + 1024 + 5120 + 2048 + 512 = 74,240 B -> 2 blocks/CU
  __shared__ __align__(16) float Wlds[256 * 64];   // swizzled weight tile
  __shared__ float bsum[256];
  __shared__ float xlds[EPB][T_ENC * 2];
  __shared__ float wih_lds[256 * 2];
  __shared__ float wemb_lds[2 * 64];

  const int tid  = threadIdx.x;
  const int lane = tid & 63;
  const int wid  = tid >> 6;
  const int beb  = blockIdx.x * EPB;   // block's first batch element

  // ---- stage x (coalesced) ----
  for (int i = tid; i < EPB * T_ENC * 2; i += 256) {
    xlds[i / 40][i % 40] = x[(size_t)beb * 40 + i];
  }
  // ---- encoder W_hh, XOR-swizzled in 16B groups:
  // store W[row][k] at row*64 + (((k>>2) ^ (row&15))<<2) + (k&3)
  for (int i = tid; i < 256 * 64; i += 256) {
    int row = i >> 6, k = i & 63;
    Wlds[(row << 6) | (((((k >> 2) ^ row) & 15)) << 2) | (k & 3)] = W_hh_enc[i];
  }
  if (tid < 256) bsum[tid] = b_ih_enc[tid] + b_hh_enc[tid];
  for (int i = tid; i < 512; i += 256) wih_lds[i] = W_ih_enc[i];
  __syncthreads();

  float h[EPW], c[EPW];
#pragma unroll
  for (int e = 0; e < EPW; e++) { h[e] = 0.0f; c[e] = 0.0f; }

  // per-lane gate rows: row = g*64 + lane
  float wi0[4], wi1[4], bsl[4];
#pragma unroll
  for (int g = 0; g < 4; g++) {
    wi0[g] = wih_lds[(g * 64 + lane) * 2 + 0];
    wi1[g] = wih_lds[(g * 64 + lane) * 2 + 1];
    bsl[g] = bsum[g * 64 + lane];
  }

  // gates[e][g*64+lane] += sum_k h[e][k] * Wlds_row(g*64+lane)[k]
  auto gemm_acc = [&](float (&acc)[EPW][4], const float (&hr)[EPW]) {
#pragma unroll 2
    for (int k0 = 0; k0 < 64; k0 += 4) {
      const int swz = ((((k0 >> 2) ^ lane) & 15) << 2);
      const float4 wv0 = *(const float4*)&Wlds[(0 << 12) + (lane << 6) + swz];
      const float4 wv1 = *(const float4*)&Wlds[(1 << 12) + (lane << 6) + swz];
      const float4 wv2 = *(const float4*)&Wlds[(2 << 12) + (lane << 6) + swz];
      const float4 wv3 = *(const float4*)&Wlds[(3 << 12) + (lane << 6) + swz];
#pragma unroll
      for (int e = 0; e < EPW; e++) {
        const float hk0 = rdlane(hr[e], k0 + 0);  // SGPR broadcast
        const float hk1 = rdlane(hr[e], k0 + 1);
        const float hk2 = rdlane(hr[e], k0 + 2);
        const float hk3 = rdlane(hr[e], k0 + 3);
        acc[e][0] = fmaf(hk0, wv0.x, acc[e][0]);
        acc[e][0] = fmaf(hk1, wv0.y, acc[e][0]);
        acc[e][0] = fmaf(hk2, wv0.z, acc[e][0]);
        acc[e][0] = fmaf(hk3, wv0.w, acc[e][0]);
        acc[e][1] = fmaf(hk0, wv1.x, acc[e][1]);
        acc[e][1] = fmaf(hk1, wv1.y, acc[e][1]);
        acc[e][1] = fmaf(hk2, wv1.z, acc[e][1]);
        acc[e][1] = fmaf(hk3, wv1.w, acc[e][1]);
        acc[e][2] = fmaf(hk0, wv2.x, acc[e][2]);
        acc[e][2] = fmaf(hk1, wv2.y, acc[e][2]);
        acc[e][2] = fmaf(hk2, wv2.z, acc[e][2]);
        acc[e][2] = fmaf(hk3, wv2.w, acc[e][2]);
        acc[e][3] = fmaf(hk0, wv3.x, acc[e][3]);
        acc[e][3] = fmaf(hk1, wv3.y, acc[e][3]);
        acc[e][3] = fmaf(hk2, wv3.z, acc[e][3]);
        acc[e][3] = fmaf(hk3, wv3.w, acc[e][3]);
      }
    }
  };

  auto cell_update = [&](float (&a4)[4], float& hh, float& cc) {
    const float ig = fast_sigmoid(a4[0]);
    const float fg = fast_sigmoid(a4[1]);
    const float gg = fast_tanh(a4[2]);
    const float og = fast_sigmoid(a4[3]);
    cc = fmaf(fg, cc, ig * gg);
    hh = og * fast_tanh(cc);
  };

  // ================= encoder =================
#pragma unroll 1
  for (int t = 0; t < T_ENC; t++) {
    float acc[EPW][4];
#pragma unroll
    for (int e = 0; e < EPW; e++) {
      const float x0 = xlds[wid * EPW + e][2 * t + 0];  // uniform -> broadcast
      const float x1 = xlds[wid * EPW + e][2 * t + 1];
#pragma unroll
      for (int g = 0; g < 4; g++)
        acc[e][g] = fmaf(x0, wi0[g], fmaf(x1, wi1[g], bsl[g]));
    }
    gemm_acc(acc, h);
#pragma unroll
    for (int e = 0; e < EPW; e++) cell_update(acc[e], h[e], c[e]);
  }

  // ================= swap weights to decoder =================
  // decoder input == h, so gates = h @ (W_ih_dec + W_hh_dec)^T + (b_ih + b_hh)
  __syncthreads();
  for (int i = tid; i < 256 * 64; i += 256) {
    int row = i >> 6, k = i & 63;
    Wlds[(row << 6) | (((((k >> 2) ^ row) & 15)) << 2) | (k & 3)] =
        W_ih_dec[i] + W_hh_dec[i];
  }
  if (tid < 256) bsum[tid] = b_ih_dec[tid] + b_hh_dec[tid];
  if (tid < 128) wemb_lds[tid] = W_emb[tid];
  __syncthreads();

#pragma unroll
  for (int g = 0; g < 4; g++) bsl[g] = bsum[g * 64 + lane];
  const float we0 = wemb_lds[lane];
  const float we1 = wemb_lds[64 + lane];
  const float be0 = b_emb[0];
  const float be1 = b_emb[1];

  // ================= decoder =================
#pragma unroll 1
  for (int t = 0; t < T_DEC; t++) {
    float acc[EPW][4];
#pragma unroll
    for (int e = 0; e < EPW; e++)
#pragma unroll
      for (int g = 0; g < 4; g++) acc[e][g] = bsl[g];
    gemm_acc(acc, h);
#pragma unroll
    for (int e = 0; e < EPW; e++) cell_update(acc[e], h[e], c[e]);

    // pos[e][d] = b_emb[d] + sum_j h[e][j] * W_emb[d][j] : cross-lane reduce
#pragma unroll
    for (int e = 0; e < EPW; e++) {
      float p0 = h[e] * we0;
      float p1 = h[e] * we1;
#pragma unroll
      for (int m = 32; m >= 1; m >>= 1) {
        p0 += __shfl_xor(p0, m, 64);
        p1 += __shfl_xor(p1, m, 64);
      }
      if (lane == 0) {
        float2 v;
        v.x = p0 + be0;
        v.y = p1 + be1;
        *(float2*)&out[(size_t)(beb + wid * EPW + e) * 60 + 2 * t] = v;
      }
    }
  }
}

extern "C" void kernel_launch(void* const* d_in, const int* in_sizes, int n_in,
                              void* d_out, int out_size, void* d_ws, size_t ws_size,
                              hipStream_t stream) {
  const float* x        = (const float*)d_in[0];
  const float* W_ih_enc = (const float*)d_in[1];
  const float* W_hh_enc = (const float*)d_in[2];
  const float* b_ih_enc = (const float*)d_in[3];
  const float* b_hh_enc = (const float*)d_in[4];
  const float* W_ih_dec = (const float*)d_in[5];
  const float* W_hh_dec = (const float*)d_in[6];
  const float* b_ih_dec = (const float*)d_in[7];
  const float* b_hh_dec = (const float*)d_in[8];
  const float* W_emb    = (const float*)d_in[9];
  const float* b_emb    = (const float*)d_in[10];
  float* out = (float*)d_out;

  const int B = in_sizes[0] / (T_ENC * 2);   // 65536
  const int grid = B / EPB;                  // 2048 (B divisible by 32)

  hipLaunchKernelGGL(SinglePrediction_88493506167138_kernel,
                     dim3(grid), dim3(256), 0, stream,
                     x, W_ih_enc, W_hh_enc, b_ih_enc, b_hh_enc,
                     W_ih_dec, W_hh_dec, b_ih_dec, b_hh_dec,
                     W_emb, b_emb, out);
}

// Round 2
// 735.982 us; speedup vs baseline: 2.6704x; 2.6704x over previous
//
#include <hip/hip_runtime.h>

#define T_ENC 20
#define T_DEC 30
#define WAVES 4           // 4 waves/block, 32 batch elements per wave
#define EPB (WAVES * 32)  // 128 elements per block

typedef __attribute__((ext_vector_type(8))) short short8;    // 8 bf16 = 4 VGPR
typedef __attribute__((ext_vector_type(16))) float f32x16;   // MFMA 32x32 acc

#if __has_builtin(__builtin_amdgcn_exp2f)
#define EXP2F(x) __builtin_amdgcn_exp2f(x)
#else
#define EXP2F(x) exp2f(x)
#endif
#if __has_builtin(__builtin_amdgcn_rcpf)
#define RCPF(x) __builtin_amdgcn_rcpf(x)
#else
#define RCPF(x) (1.0f / (x))
#endif

__device__ __forceinline__ float fast_sigmoid(float x) {
  float e = EXP2F(-1.4426950408889634f * x);
  return RCPF(1.0f + e);
}
__device__ __forceinline__ float fast_tanh(float x) {
  float e = EXP2F(2.8853900817779268f * x);
  return 1.0f - 2.0f * RCPF(e + 1.0f);
}

__device__ __forceinline__ unsigned short f2bf(float f) {  // RNE fp32->bf16
  unsigned u = __float_as_uint(f);
  u += 0x7fffu + ((u >> 16) & 1u);
  return (unsigned short)(u >> 16);
}
__device__ __forceinline__ float bf2f(unsigned short b) {
  return __uint_as_float(((unsigned)b) << 16);
}

#define MFMA32(a, b, c) __builtin_amdgcn_mfma_f32_32x32x16_bf16(a, b, c, 0, 0, 0)

__global__ __launch_bounds__(256, 1)
void SinglePrediction_88493506167138_kernel(
    const float* __restrict__ x,         // [B][20][2]
    const float* __restrict__ W_ih_enc,  // [256][2]
    const float* __restrict__ W_hh_enc,  // [256][64]
    const float* __restrict__ b_ih_enc,  // [256]
    const float* __restrict__ b_hh_enc,  // [256]
    const float* __restrict__ W_ih_dec,  // [256][64]
    const float* __restrict__ W_hh_dec,  // [256][64]
    const float* __restrict__ b_ih_dec,  // [256]
    const float* __restrict__ b_hh_dec,  // [256]
    const float* __restrict__ W_emb,     // [2][64]
    const float* __restrict__ b_emb,     // [2]
    float* __restrict__ out)             // [B][30][2]
{
  // LDS: 65536 (W hi/lo) + 32768 (hT) + 20480 (x) + 1024 (bias) = 119,808 B
  __shared__ __align__(16) unsigned short Wbf[2][256 * 64]; // swizzled bf16 W
  __shared__ __align__(16) unsigned short hT[WAVES][2][32 * 64]; // h transpose
  __shared__ __align__(16) float xlds[WAVES][32][T_ENC * 2];
  __shared__ float bsum_l[256];

  const int tid = threadIdx.x;
  const int lane = tid & 63;
  const int wid = tid >> 6;
  const int hi5 = lane >> 5;       // which 32-lane half
  const int l31 = lane & 31;
  const int beb = blockIdx.x * EPB;

  // ---- stage x (contiguous: xlds flat == x[beb*40 ..]) ----
  {
    const float4* src = (const float4*)(x + (size_t)beb * (T_ENC * 2));
    float4* dst = (float4*)&xlds[0][0][0];
    for (int i = tid; i < EPB * T_ENC * 2 / 4; i += 256) dst[i] = src[i];
  }
  // ---- stage encoder W_hh as bf16 hi/lo, XOR-swizzled (k ^= (row&7)<<3) ----
  for (int i = tid; i < 256 * 64; i += 256) {
    int row = i >> 6, k = i & 63;
    float w = W_hh_enc[i];
    unsigned short hb = f2bf(w);
    unsigned short lb = f2bf(w - bf2f(hb));
    int si = (row << 6) | (k ^ ((row & 7) << 3));
    Wbf[0][si] = hb;
    Wbf[1][si] = lb;
  }
  bsum_l[tid] = b_ih_enc[tid] + b_hh_enc[tid];
  // ---- zero this wave's hT (h0 = 0) ----
  {
    float4 z = {0.f, 0.f, 0.f, 0.f};
    float4* p = (float4*)&hT[wid][0][0];
    for (int i = lane; i < 512; i += 64) p[i] = z;
  }
  __syncthreads();

  // per-lane constants (gate row n = nt*32 + l31)
  float biasv[8], wi0[8], wi1[8];
#pragma unroll
  for (int nt = 0; nt < 8; nt++) {
    int n = nt * 32 + l31;
    biasv[nt] = bsum_l[n];
    float2 wv = *(const float2*)&W_ih_enc[2 * n];
    wi0[nt] = wv.x;
    wi1[nt] = wv.y;
  }

  float c01[2][16];
#pragma unroll
  for (int p = 0; p < 2; p++)
#pragma unroll
    for (int q = 0; q < 16; q++) c01[p][q] = 0.f;

  const int sw = (l31 & 7) << 3;          // swizzle term (same for A and B)
  const int kbase = hi5 << 3;             // k-offset of this lane half

  // ================= encoder =================
#pragma unroll 1
  for (int t = 0; t < T_ENC; t++) {
    short8 ah[4], al[4];
#pragma unroll
    for (int kt = 0; kt < 4; kt++) {
      int sk = (kt * 16 + kbase) ^ sw;
      ah[kt] = *(const short8*)&hT[wid][0][(l31 << 6) + sk];
      al[kt] = *(const short8*)&hT[wid][1][(l31 << 6) + sk];
    }
    float2 xr[16];
#pragma unroll
    for (int q = 0; q < 16; q++) {
      int row = (q & 3) + 8 * (q >> 2) + 4 * hi5;
      xr[q] = *(const float2*)&xlds[wid][row][2 * t];
    }
    f32x16 acc[8];
#pragma unroll
    for (int nt = 0; nt < 8; nt++)
#pragma unroll
      for (int q = 0; q < 16; q++)
        acc[nt][q] = fmaf(xr[q].x, wi0[nt], fmaf(xr[q].y, wi1[nt], biasv[nt]));
#pragma unroll
    for (int kt = 0; kt < 4; kt++) {
      short8 bh[8], bl[8];
      int sk = (kt * 16 + kbase) ^ sw;
#pragma unroll
      for (int nt = 0; nt < 8; nt++) {
        int r = nt * 32 + l31;
        bh[nt] = *(const short8*)&Wbf[0][(r << 6) + sk];
        bl[nt] = *(const short8*)&Wbf[1][(r << 6) + sk];
      }
#pragma unroll
      for (int nt = 0; nt < 8; nt++) acc[nt] = MFMA32(ah[kt], bh[nt], acc[nt]);
#pragma unroll
      for (int nt = 0; nt < 8; nt++) acc[nt] = MFMA32(al[kt], bh[nt], acc[nt]);
#pragma unroll
      for (int nt = 0; nt < 8; nt++) acc[nt] = MFMA32(ah[kt], bl[nt], acc[nt]);
    }
#pragma unroll
    for (int p = 0; p < 2; p++)
#pragma unroll
      for (int q = 0; q < 16; q++) {
        float ig = fast_sigmoid(acc[0 + p][q]);
        float fg = fast_sigmoid(acc[2 + p][q]);
        float gg = fast_tanh(acc[4 + p][q]);
        float og = fast_sigmoid(acc[6 + p][q]);
        float cn = fmaf(fg, c01[p][q], ig * gg);
        c01[p][q] = cn;
        float hn = og * fast_tanh(cn);
        unsigned short hb = f2bf(hn);
        unsigned short lb = f2bf(hn - bf2f(hb));
        int row = (q & 3) + 8 * (q >> 2) + 4 * hi5;
        int col = l31 + 32 * p;
        int si = (row << 6) | (col ^ ((row & 7) << 3));
        hT[wid][0][si] = hb;
        hT[wid][1][si] = lb;
      }
  }

  // ================= swap to decoder weights =================
  __syncthreads();
  for (int i = tid; i < 256 * 64; i += 256) {
    int row = i >> 6, k = i & 63;
    float w = W_ih_dec[i] + W_hh_dec[i];
    unsigned short hb = f2bf(w);
    unsigned short lb = f2bf(w - bf2f(hb));
    int si = (row << 6) | (k ^ ((row & 7) << 3));
    Wbf[0][si] = hb;
    Wbf[1][si] = lb;
  }
  bsum_l[tid] = b_ih_dec[tid] + b_hh_dec[tid];
  __syncthreads();

#pragma unroll
  for (int nt = 0; nt < 8; nt++) biasv[nt] = bsum_l[nt * 32 + l31];
  const float we00 = W_emb[l31];           // W_emb[0][j]
  const float we01 = W_emb[32 + l31];      // W_emb[0][j+32]
  const float we10 = W_emb[64 + l31];      // W_emb[1][j]
  const float we11 = W_emb[96 + l31];      // W_emb[1][j+32]
  const float be0 = b_emb[0];
  const float be1 = b_emb[1];

  // ================= decoder =================
#pragma unroll 1
  for (int t = 0; t < T_DEC; t++) {
    short8 ah[4], al[4];
#pragma unroll
    for (int kt = 0; kt < 4; kt++) {
      int sk = (kt * 16 + kbase) ^ sw;
      ah[kt] = *(const short8*)&hT[wid][0][(l31 << 6) + sk];
      al[kt] = *(const short8*)&hT[wid][1][(l31 << 6) + sk];
    }
    f32x16 acc[8];
#pragma unroll
    for (int nt = 0; nt < 8; nt++)
#pragma unroll
      for (int q = 0; q < 16; q++) acc[nt][q] = biasv[nt];
#pragma unroll
    for (int kt = 0; kt < 4; kt++) {
      short8 bh[8], bl[8];
      int sk = (kt * 16 + kbase) ^ sw;
#pragma unroll
      for (int nt = 0; nt < 8; nt++) {
        int r = nt * 32 + l31;
        bh[nt] = *(const short8*)&Wbf[0][(r << 6) + sk];
        bl[nt] = *(const short8*)&Wbf[1][(r << 6) + sk];
      }
#pragma unroll
      for (int nt = 0; nt < 8; nt++) acc[nt] = MFMA32(ah[kt], bh[nt], acc[nt]);
#pragma unroll
      for (int nt = 0; nt < 8; nt++) acc[nt] = MFMA32(al[kt], bh[nt], acc[nt]);
#pragma unroll
      for (int nt = 0; nt < 8; nt++) acc[nt] = MFMA32(ah[kt], bl[nt], acc[nt]);
    }
    float hs[2][16];
#pragma unroll
    for (int p = 0; p < 2; p++)
#pragma unroll
      for (int q = 0; q < 16; q++) {
        float ig = fast_sigmoid(acc[0 + p][q]);
        float fg = fast_sigmoid(acc[2 + p][q]);
        float gg = fast_tanh(acc[4 + p][q]);
        float og = fast_sigmoid(acc[6 + p][q]);
        float cn = fmaf(fg, c01[p][q], ig * gg);
        c01[p][q] = cn;
        float hn = og * fast_tanh(cn);
        hs[p][q] = hn;
        unsigned short hb = f2bf(hn);
        unsigned short lb = f2bf(hn - bf2f(hb));
        int row = (q & 3) + 8 * (q >> 2) + 4 * hi5;
        int col = l31 + 32 * p;
        int si = (row << 6) | (col ^ ((row & 7) << 3));
        hT[wid][0][si] = hb;
        hT[wid][1][si] = lb;
      }
    // pos: per q, reduce h[row]·W_emb over j across the 32-lane half
#pragma unroll
    for (int q = 0; q < 16; q++) {
      float p0 = fmaf(hs[0][q], we00, hs[1][q] * we01);
      float p1 = fmaf(hs[0][q], we10, hs[1][q] * we11);
#pragma unroll
      for (int m = 16; m >= 1; m >>= 1) {
        p0 += __shfl_xor(p0, m, 64);
        p1 += __shfl_xor(p1, m, 64);
      }
      if (l31 == 0) {
        int row = (q & 3) + 8 * (q >> 2) + 4 * hi5;
        float2 v;
        v.x = p0 + be0;
        v.y = p1 + be1;
        *(float2*)&out[(size_t)(beb + wid * 32 + row) * 60 + 2 * t] = v;
      }
    }
  }
}

extern "C" void kernel_launch(void* const* d_in, const int* in_sizes, int n_in,
                              void* d_out, int out_size, void* d_ws, size_t ws_size,
                              hipStream_t stream) {
  const float* x        = (const float*)d_in[0];
  const float* W_ih_enc = (const float*)d_in[1];
  const float* W_hh_enc = (const float*)d_in[2];
  const float* b_ih_enc = (const float*)d_in[3];
  const float* b_hh_enc = (const float*)d_in[4];
  const float* W_ih_dec = (const float*)d_in[5];
  const float* W_hh_dec = (const float*)d_in[6];
  const float* b_ih_dec = (const float*)d_in[7];
  const float* b_hh_dec = (const float*)d_in[8];
  const float* W_emb    = (const float*)d_in[9];
  const float* b_emb    = (const float*)d_in[10];
  float* out = (float*)d_out;

  const int B = in_sizes[0] / (T_ENC * 2);  // 65536
  const int grid = B / EPB;                 // 512

  hipLaunchKernelGGL(SinglePrediction_88493506167138_kernel,
                     dim3(grid), dim3(256), 0, stream,
                     x, W_ih_enc, W_hh_enc, b_ih_enc, b_hh_enc,
                     W_ih_dec, W_hh_dec, b_ih_dec, b_hh_dec,
                     W_emb, b_emb, out);
}